// Round 12
// baseline (211.805 us; speedup 1.0000x reference)
//
#include <hip/hip_runtime.h>
#include <math.h>

#define T_DIM 11
#define HH 1024
#define WW 1024
#define HWSZ (HH*WW)
#define INTR 1022              // interior extent (1..1022 in full image)
#define NSTRIP 511             // 1022 interior cols / 2 per thread

struct FracM { float m[T_DIM][T_DIM]; };

// stencil coefficients (from LAPL / PX / PY), with /DX and /DX^2 folded in
#define LC0 0.34520446044393f        // laplacian corners
#define LC1 0.309591078922457f       // laplacian edges
#define LCC -2.619182157203629f      // laplacian center
#define PA  0.086301115118584f       // deriv corner coeff
#define PB  0.32739776970073f        // deriv edge coeff
#define INV_DX  1024.0f
#define INV_DX2 1048576.0f
#define R_COEF 0.01f

// pack two f32 as bf16 (truncated) into one u32: hi=a, lo=b
__device__ __forceinline__ unsigned int pack_bf2(float a, float b)
{
    return (__float_as_uint(a) & 0xffff0000u) | (__float_as_uint(b) >> 16);
}
__device__ __forceinline__ float unpack_hi(unsigned int r) { return __uint_as_float(r & 0xffff0000u); }
__device__ __forceinline__ float unpack_lo(unsigned int r) { return __uint_as_float(r << 16); }

// derived stencil values for the 2-pixel strip of ONE channel:
// lap/gx/gy per pixel + the two center values. Consumes the 6-float2 window
// immediately so its 12 registers retire before the next channel loads.
struct Deriv { float lap0, gx0, gy0, lap1, gx1, gy1, c0, c1; };

__device__ __forceinline__ Deriv window_derive(const float* __restrict__ base, int c)
{
    const float2 TL = *(const float2*)(base + c - WW - 1);
    const float2 TR = *(const float2*)(base + c - WW + 1);
    const float2 ML = *(const float2*)(base + c - 1);
    const float2 MR = *(const float2*)(base + c + 1);
    const float2 BL = *(const float2*)(base + c + WW - 1);
    const float2 BR = *(const float2*)(base + c + WW + 1);

    Deriv d;
    d.c0 = ML.y;  d.c1 = MR.x;
    // px0 window: TL.x TL.y TR.x / ML.x ML.y MR.x / BL.x BL.y BR.x
    d.lap0 = (LC0*(TL.x+TR.x+BL.x+BR.x) + LC1*(TL.y+ML.x+MR.x+BL.y) + LCC*ML.y) * INV_DX2;
    d.gx0  = (PA*(TR.x-TL.x) + PB*(MR.x-ML.x) + PA*(BR.x-BL.x)) * INV_DX;
    d.gy0  = (PA*(BL.x-TL.x) + PB*(BL.y-TL.y) + PA*(BR.x-TR.x)) * INV_DX;
    // px1 window: TL.y TR.x TR.y / ML.y MR.x MR.y / BL.y BR.x BR.y
    d.lap1 = (LC0*(TL.y+TR.y+BL.y+BR.y) + LC1*(TR.x+ML.y+MR.y+BR.x) + LCC*MR.x) * INV_DX2;
    d.gx1  = (PA*(TR.y-TL.y) + PB*(MR.y-ML.y) + PA*(BR.y-BL.y)) * INV_DX;
    d.gy1  = (PA*(BL.y-TL.y) + PB*(BR.x-TR.x) + PA*(BR.y-TR.y)) * INV_DX;
    return d;
}

// R9: natural pressure hit 68 VGPR (4 over the 64 cliff) -> 4 waves/SIMD,
// 27.7% occupancy, still latency-bound at 74.9us. This round: clamp to the
// 64-reg bucket with (256,4) -- safe now the gap is 4 regs, not 70 (R5) --
// and restructure u-then-v so peak window liveness halves.
__global__ __launch_bounds__(256, 4)
void fused_loss_kernel(const float* __restrict__ uv,   // [T,2,H,W]
                       const float* __restrict__ f1,   // [T,1,H,W]
                       const float* __restrict__ f2,   // [T,1,H,W]
                       double* __restrict__ partial,
                       FracM M)
{
    __shared__ unsigned int hist_u[T_DIM][256];
    __shared__ unsigned int hist_v[T_DIM][256];

    const int tid = threadIdx.x;
    // each thread: 2 horizontal pixels (one strip), consecutive lanes = consecutive strips
    const int sb = blockIdx.x * 64 + (tid & 63);   // strip 0..510
    const int i  = blockIdx.y * 4  + (tid >> 6);   // interior row 0..1021

    float acc = 0.0f;

    if (sb < NSTRIP && i < INTR) {
        const int ci = i + 1;
        const int j0 = 1 + 2 * sb;            // full-image col of px0 (odd)
        const int c  = ci * WW + j0;          // center index of px0; c-1 is 8B-aligned

        #pragma unroll
        for (int t = 0; t < T_DIM; ++t) {
            const float* ub = uv + (size_t)(2 * t) * HWSZ;
            const float* vb = ub + HWSZ;

            // u channel: load window, derive, retire window regs
            const Deriv du = window_derive(ub, c);
            // v channel
            const Deriv dv = window_derive(vb, c);

            const float* f1p = f1 + (size_t)t * HWSZ;
            const float* f2p = f2 + (size_t)t * HWSZ;
            const float f1a = f1p[c], f1b = f1p[c + 1];
            const float f2a = f2p[c], f2b = f2p[c + 1];

            // fractional derivative: bf16 history (LDS) for s<t, exact f32 diagonal s==t
            float Du0 = 0.f, Dv0 = 0.f, Du1 = 0.f, Dv1 = 0.f;
            #pragma unroll
            for (int s = 0; s < t; ++s) {
                const float m = M.m[t][s];
                const unsigned int ru = hist_u[s][tid];
                const unsigned int rv = hist_v[s][tid];
                Du0 += m * unpack_hi(ru); Du1 += m * unpack_lo(ru);
                Dv0 += m * unpack_hi(rv); Dv1 += m * unpack_lo(rv);
            }
            {
                const float m = M.m[t][t];   // row 0 is all zeros -> Du stays 0 at t=0
                Du0 += m * du.c0; Du1 += m * du.c1;
                Dv0 += m * dv.c0; Dv1 += m * dv.c1;
            }
            hist_u[t][tid] = pack_bf2(du.c0, du.c1);
            hist_v[t][tid] = pack_bf2(dv.c0, dv.c1);

            const float fu0 = Du0 + du.c0*du.gx0 + dv.c0*du.gy0 - R_COEF*du.lap0 - f1a;
            const float fv0 = Dv0 + du.c0*dv.gx0 + dv.c0*dv.gy0 - R_COEF*dv.lap0 - f2a;
            const float fu1 = Du1 + du.c1*du.gx1 + dv.c1*du.gy1 - R_COEF*du.lap1 - f1b;
            const float fv1 = Dv1 + du.c1*dv.gx1 + dv.c1*dv.gy1 - R_COEF*dv.lap1 - f2b;

            acc += fu0*fu0 + fv0*fv0 + fu1*fu1 + fv1*fv1;
        }
    }

    // ---- reduction: wave64 shfl -> LDS -> one fp64 atomic per block ----
    double dacc = (double)acc;
    #pragma unroll
    for (int off = 32; off > 0; off >>= 1)
        dacc += __shfl_down(dacc, off, 64);

    __shared__ double sdata[4];
    const int lane = tid & 63;
    const int wid  = tid >> 6;
    if (lane == 0) sdata[wid] = dacc;
    __syncthreads();
    if (tid == 0) {
        const double tot = sdata[0] + sdata[1] + sdata[2] + sdata[3];
        atomicAdd(partial, tot);
    }
}

__global__ void finalize_kernel(const double* __restrict__ partial, float* __restrict__ out)
{
    const double n = (double)T_DIM * (double)INTR * (double)INTR;
    out[0] = (float)(partial[0] / n);
}

static FracM make_frac_matrix()
{
    const double alpha = 0.5;
    const int n = 9;                      // N_FRAC
    double w[n + 1];
    w[0] = 1.0;
    for (int jj = 1; jj <= n; ++jj)
        w[jj] = pow((double)(jj + 1), 1.0 - alpha) - pow((double)jj, 1.0 - alpha);

    double M[T_DIM][T_DIM] = {};
    for (int i = 1; i <= n + 1; ++i) {
        M[i][i] += w[0];
        M[i][0] -= w[i - 1];
        for (int k = 1; k < i; ++k)
            M[i][k] -= (w[i - k - 1] - w[i - k]);
    }
    const double scale = pow(0.1, -alpha) / tgamma(2.0 - alpha);  // DT^-a / gamma(2-a)

    FracM f;
    for (int i = 0; i < T_DIM; ++i)
        for (int jj = 0; jj < T_DIM; ++jj)
            f.m[i][jj] = (float)(M[i][jj] * scale);
    return f;
}

extern "C" void kernel_launch(void* const* d_in, const int* in_sizes, int n_in,
                              void* d_out, int out_size, void* d_ws, size_t ws_size,
                              hipStream_t stream)
{
    const float* uv = (const float*)d_in[0];   // output [T,2,H,W]
    const float* f1 = (const float*)d_in[1];   // [T,1,H,W]
    const float* f2 = (const float*)d_in[2];   // [T,1,H,W]
    float* out      = (float*)d_out;
    double* partial = (double*)d_ws;

    FracM M = make_frac_matrix();

    hipMemsetAsync(partial, 0, sizeof(double), stream);

    dim3 block(256, 1, 1);
    dim3 grid((NSTRIP + 63) / 64, (INTR + 3) / 4, 1);   // 8 x 256
    fused_loss_kernel<<<grid, block, 0, stream>>>(uv, f1, f2, partial, M);

    finalize_kernel<<<1, 1, 0, stream>>>(partial, out);
}